// Round 2
// baseline (2784.227 us; speedup 1.0000x reference)
//
#include <hip/hip_runtime.h>

#define N_NODES 50000
#define N_EDGES 1600000
#define IN_F 128
#define OUT_F 128   // HEADS*HEAD_DIM
#define HEADS 4
#define HEAD_DIM 32
#define NEG_SLOPE 0.2f

// ---------------------------------------------------------------------------
// Kernel A: h = x @ W^T  (row-major h[n][o]), plus per-node attention scalars
//   alpha_s[n][head] = sum_d h[n,head,d] * a[head][d]
//   alpha_d[n][head] = sum_d h[n,head,d] * a[head][32+d]
// Block = 256 threads, 8 nodes per block, grid = 50000/8 = 6250.
// ---------------------------------------------------------------------------
__global__ __launch_bounds__(256) void gemm_alpha_kernel(
    const float* __restrict__ x, const float* __restrict__ W,
    const float* __restrict__ a,
    float* __restrict__ h, float* __restrict__ alpha_s, float* __restrict__ alpha_d)
{
    __shared__ float Wlds[128][129];
    __shared__ float xs[8][128];

    const int tid = threadIdx.x;
    const int node0 = blockIdx.x * 8;

    // Load W (128x128 f32) into LDS. 4096 float4 total, 16 per thread.
    {
        const float4* W4 = (const float4*)W;
        #pragma unroll
        for (int it = 0; it < 16; ++it) {
            int i = tid + it * 256;           // float4 linear index
            int o = i >> 5, k4 = i & 31;
            float4 w = W4[i];
            Wlds[o][k4 * 4 + 0] = w.x;
            Wlds[o][k4 * 4 + 1] = w.y;
            Wlds[o][k4 * 4 + 2] = w.z;
            Wlds[o][k4 * 4 + 3] = w.w;
        }
    }
    // Load 8 x rows (8*32 = 256 float4, one per thread).
    {
        const float4* x4 = (const float4*)x;
        int n = tid >> 5, k4 = tid & 31;
        float4 v = x4[(size_t)(node0 + n) * 32 + k4];
        xs[n][k4 * 4 + 0] = v.x;
        xs[n][k4 * 4 + 1] = v.y;
        xs[n][k4 * 4 + 2] = v.z;
        xs[n][k4 * 4 + 3] = v.w;
    }
    __syncthreads();

    const int o = tid & 127;
    const int g = tid >> 7;      // which half: nodes [g*4, g*4+4)
    const int nbase = g * 4;

    float acc0 = 0.f, acc1 = 0.f, acc2 = 0.f, acc3 = 0.f;
    #pragma unroll 8
    for (int kc = 0; kc < 32; ++kc) {
        float w0 = Wlds[o][kc * 4 + 0];
        float w1 = Wlds[o][kc * 4 + 1];
        float w2 = Wlds[o][kc * 4 + 2];
        float w3 = Wlds[o][kc * 4 + 3];
        float4 xv0 = *(const float4*)&xs[nbase + 0][kc * 4];
        float4 xv1 = *(const float4*)&xs[nbase + 1][kc * 4];
        float4 xv2 = *(const float4*)&xs[nbase + 2][kc * 4];
        float4 xv3 = *(const float4*)&xs[nbase + 3][kc * 4];
        acc0 = fmaf(w0, xv0.x, fmaf(w1, xv0.y, fmaf(w2, xv0.z, fmaf(w3, xv0.w, acc0))));
        acc1 = fmaf(w0, xv1.x, fmaf(w1, xv1.y, fmaf(w2, xv1.z, fmaf(w3, xv1.w, acc1))));
        acc2 = fmaf(w0, xv2.x, fmaf(w1, xv2.y, fmaf(w2, xv2.z, fmaf(w3, xv2.w, acc2))));
        acc3 = fmaf(w0, xv3.x, fmaf(w1, xv3.y, fmaf(w2, xv3.z, fmaf(w3, xv3.w, acc3))));
    }

    const int head = o >> 5;
    const int d = o & 31;
    const float a_s = a[head * 64 + d];
    const float a_d = a[head * 64 + 32 + d];

    float accs[4] = {acc0, acc1, acc2, acc3};
    #pragma unroll
    for (int n = 0; n < 4; ++n) {
        const int node = node0 + nbase + n;
        h[(size_t)node * 128 + o] = accs[n];
        float s = accs[n] * a_s;
        float t = accs[n] * a_d;
        #pragma unroll
        for (int off = 16; off >= 1; off >>= 1) {
            s += __shfl_xor(s, off);
            t += __shfl_xor(t, off);
        }
        if (d == 0) {
            alpha_s[node * 4 + head] = s;
            alpha_d[node * 4 + head] = t;
        }
    }
}

// ---------------------------------------------------------------------------
// Kernel B: per-edge scatter. 32 lanes per edge; lane c owns float4 chunk c
// of the 128-float feature row (512B per edge, coalesced).
//   out[dst] += leaky_relu(alpha_s[src,head] + alpha_d[dst,head]) * h[src]
// Edge indices arrive as int32 (harness converts integer inputs to int).
// ---------------------------------------------------------------------------
__global__ __launch_bounds__(256) void edge_kernel(
    const int* __restrict__ ei,
    const float* __restrict__ h,
    const float* __restrict__ alpha_s, const float* __restrict__ alpha_d,
    float* __restrict__ out)
{
    const unsigned total = (unsigned)N_EDGES * 32u;
    const unsigned stride = gridDim.x * blockDim.x;
    for (unsigned i = blockIdx.x * blockDim.x + threadIdx.x; i < total; i += stride) {
        const int e = (int)(i >> 5);
        const int c = (int)(i & 31);
        const int src = ei[e];
        const int dst = ei[N_EDGES + e];
        const int head = c >> 3;

        float att = alpha_s[src * 4 + head] + alpha_d[dst * 4 + head];
        att = att > 0.f ? att : NEG_SLOPE * att;

        const float4 hv = ((const float4*)h)[(size_t)src * 32 + c];
        float* po = out + (size_t)dst * 128 + c * 4;
        atomicAdd(po + 0, att * hv.x);
        atomicAdd(po + 1, att * hv.y);
        atomicAdd(po + 2, att * hv.z);
        atomicAdd(po + 3, att * hv.w);
    }
}

extern "C" void kernel_launch(void* const* d_in, const int* in_sizes, int n_in,
                              void* d_out, int out_size, void* d_ws, size_t ws_size,
                              hipStream_t stream) {
    const float* x  = (const float*)d_in[0];
    const int*   ei = (const int*)d_in[1];
    const float* W  = (const float*)d_in[2];
    const float* a  = (const float*)d_in[3];
    float* out = (float*)d_out;

    // Workspace layout: h (50000*128 f32) | alpha_s (50000*4) | alpha_d (50000*4)
    float* h  = (float*)d_ws;
    float* as = h + (size_t)N_NODES * 128;
    float* ad = as + (size_t)N_NODES * 4;

    hipMemsetAsync(d_out, 0, (size_t)out_size * sizeof(float), stream);

    gemm_alpha_kernel<<<N_NODES / 8, 256, 0, stream>>>(x, W, a, h, as, ad);
    edge_kernel<<<4096, 256, 0, stream>>>(ei, h, as, ad, out);
}

// Round 3
// 486.599 us; speedup vs baseline: 5.7218x; 5.7218x over previous
//
#include <hip/hip_runtime.h>

#define N_NODES 50000
#define N_EDGES 1600000
#define IN_F 128
#define OUT_F 128   // HEADS*HEAD_DIM
#define HEADS 4
#define HEAD_DIM 32
#define NEG_SLOPE 0.2f

// ---------------------------------------------------------------------------
// Kernel A: h = x @ W^T  (row-major h[n][o]), plus per-node attention scalars
//   alpha_s[n][head] = sum_d h[n,head,d] * a[head][d]
//   alpha_d[n][head] = sum_d h[n,head,d] * a[head][32+d]
// ---------------------------------------------------------------------------
__global__ __launch_bounds__(256) void gemm_alpha_kernel(
    const float* __restrict__ x, const float* __restrict__ W,
    const float* __restrict__ a,
    float* __restrict__ h, float* __restrict__ alpha_s, float* __restrict__ alpha_d)
{
    __shared__ float Wlds[128][129];
    __shared__ float xs[8][128];

    const int tid = threadIdx.x;
    const int node0 = blockIdx.x * 8;

    {
        const float4* W4 = (const float4*)W;
        #pragma unroll
        for (int it = 0; it < 16; ++it) {
            int i = tid + it * 256;
            int o = i >> 5, k4 = i & 31;
            float4 w = W4[i];
            Wlds[o][k4 * 4 + 0] = w.x;
            Wlds[o][k4 * 4 + 1] = w.y;
            Wlds[o][k4 * 4 + 2] = w.z;
            Wlds[o][k4 * 4 + 3] = w.w;
        }
    }
    {
        const float4* x4 = (const float4*)x;
        int n = tid >> 5, k4 = tid & 31;
        float4 v = x4[(size_t)(node0 + n) * 32 + k4];
        xs[n][k4 * 4 + 0] = v.x;
        xs[n][k4 * 4 + 1] = v.y;
        xs[n][k4 * 4 + 2] = v.z;
        xs[n][k4 * 4 + 3] = v.w;
    }
    __syncthreads();

    const int o = tid & 127;
    const int g = tid >> 7;
    const int nbase = g * 4;

    float acc0 = 0.f, acc1 = 0.f, acc2 = 0.f, acc3 = 0.f;
    #pragma unroll 8
    for (int kc = 0; kc < 32; ++kc) {
        float w0 = Wlds[o][kc * 4 + 0];
        float w1 = Wlds[o][kc * 4 + 1];
        float w2 = Wlds[o][kc * 4 + 2];
        float w3 = Wlds[o][kc * 4 + 3];
        float4 xv0 = *(const float4*)&xs[nbase + 0][kc * 4];
        float4 xv1 = *(const float4*)&xs[nbase + 1][kc * 4];
        float4 xv2 = *(const float4*)&xs[nbase + 2][kc * 4];
        float4 xv3 = *(const float4*)&xs[nbase + 3][kc * 4];
        acc0 = fmaf(w0, xv0.x, fmaf(w1, xv0.y, fmaf(w2, xv0.z, fmaf(w3, xv0.w, acc0))));
        acc1 = fmaf(w0, xv1.x, fmaf(w1, xv1.y, fmaf(w2, xv1.z, fmaf(w3, xv1.w, acc1))));
        acc2 = fmaf(w0, xv2.x, fmaf(w1, xv2.y, fmaf(w2, xv2.z, fmaf(w3, xv2.w, acc2))));
        acc3 = fmaf(w0, xv3.x, fmaf(w1, xv3.y, fmaf(w2, xv3.z, fmaf(w3, xv3.w, acc3))));
    }

    const int head = o >> 5;
    const int d = o & 31;
    const float a_s = a[head * 64 + d];
    const float a_d = a[head * 64 + 32 + d];

    float accs[4] = {acc0, acc1, acc2, acc3};
    #pragma unroll
    for (int n = 0; n < 4; ++n) {
        const int node = node0 + nbase + n;
        h[(size_t)node * 128 + o] = accs[n];
        float s = accs[n] * a_s;
        float t = accs[n] * a_d;
        #pragma unroll
        for (int off = 16; off >= 1; off >>= 1) {
            s += __shfl_xor(s, off);
            t += __shfl_xor(t, off);
        }
        if (d == 0) {
            alpha_s[node * 4 + head] = s;
            alpha_d[node * 4 + head] = t;
        }
    }
}

// ---------------------------------------------------------------------------
// Counting sort of edges by dst.
// ---------------------------------------------------------------------------
__global__ __launch_bounds__(256) void hist_kernel(
    const int* __restrict__ ei, int* __restrict__ deg)
{
    int stride = gridDim.x * blockDim.x;
    for (int e = blockIdx.x * blockDim.x + threadIdx.x; e < N_EDGES; e += stride)
        atomicAdd(&deg[ei[N_EDGES + e]], 1);
}

// Single-block exclusive scan: cursor[i] = sum_{j<i} deg[j].
__global__ __launch_bounds__(1024) void scan_kernel(
    const int* __restrict__ deg, int* __restrict__ cursor)
{
    const int CH = (N_NODES + 1023) / 1024;   // 49
    __shared__ int s[1024];
    const int t = threadIdx.x;
    const int lo = t * CH;
    const int hi = min(lo + CH, N_NODES);

    int sum = 0;
    for (int i = lo; i < hi; ++i) sum += deg[i];
    s[t] = sum;
    __syncthreads();
    // Hillis-Steele inclusive scan over 1024 chunk sums.
    for (int off = 1; off < 1024; off <<= 1) {
        int v = (t >= off) ? s[t - off] : 0;
        __syncthreads();
        s[t] += v;
        __syncthreads();
    }
    int running = s[t] - sum;   // exclusive base for this chunk
    for (int i = lo; i < hi; ++i) {
        cursor[i] = running;
        running += deg[i];
    }
}

__global__ __launch_bounds__(256) void scatter_kernel(
    const int* __restrict__ ei, int* __restrict__ cursor, int* __restrict__ srcs)
{
    int stride = gridDim.x * blockDim.x;
    for (int e = blockIdx.x * blockDim.x + threadIdx.x; e < N_EDGES; e += stride) {
        int src = ei[e];
        int dst = ei[N_EDGES + e];
        int pos = atomicAdd(&cursor[dst], 1);
        srcs[pos] = src;
    }
}

// ---------------------------------------------------------------------------
// Gather/accumulate: one wave per dst node. Lane owns float2 of the feature
// row (feature f = lane*2, head = lane>>4). After scatter, cursor[n] = end of
// bucket n; start = end - deg[n]. Writes out row exactly once — no atomics.
// ---------------------------------------------------------------------------
__global__ __launch_bounds__(256) void gather_kernel(
    const int* __restrict__ srcs, const int* __restrict__ cursor,
    const int* __restrict__ deg,
    const float* __restrict__ h,
    const float* __restrict__ alpha_s, const float* __restrict__ alpha_d,
    float* __restrict__ out)
{
    const int wid = (blockIdx.x * 256 + threadIdx.x) >> 6;
    if (wid >= N_NODES) return;
    const int lane = threadIdx.x & 63;
    const int n = wid;
    const int end = cursor[n];
    const int d = deg[n];
    const int start = end - d;
    const int head = lane >> 4;

    const float adv = alpha_d[n * 4 + head];
    const float2* __restrict__ h2 = (const float2*)h;

    float2 acc0 = {0.f, 0.f}, acc1 = {0.f, 0.f};
    int i = start;
    for (; i + 1 < end; i += 2) {
        int s0 = srcs[i];
        int s1 = srcs[i + 1];
        float att0 = alpha_s[s0 * 4 + head] + adv;
        float att1 = alpha_s[s1 * 4 + head] + adv;
        att0 = att0 > 0.f ? att0 : NEG_SLOPE * att0;
        att1 = att1 > 0.f ? att1 : NEG_SLOPE * att1;
        float2 hv0 = h2[(size_t)s0 * 64 + lane];
        float2 hv1 = h2[(size_t)s1 * 64 + lane];
        acc0.x = fmaf(att0, hv0.x, acc0.x);
        acc0.y = fmaf(att0, hv0.y, acc0.y);
        acc1.x = fmaf(att1, hv1.x, acc1.x);
        acc1.y = fmaf(att1, hv1.y, acc1.y);
    }
    if (i < end) {
        int s0 = srcs[i];
        float att0 = alpha_s[s0 * 4 + head] + adv;
        att0 = att0 > 0.f ? att0 : NEG_SLOPE * att0;
        float2 hv0 = h2[(size_t)s0 * 64 + lane];
        acc0.x = fmaf(att0, hv0.x, acc0.x);
        acc0.y = fmaf(att0, hv0.y, acc0.y);
    }
    float2 r = {acc0.x + acc1.x, acc0.y + acc1.y};
    ((float2*)out)[(size_t)n * 64 + lane] = r;
}

// ---------------------------------------------------------------------------
// Fallback atomic edge kernel (used only if ws_size is too small for CSR).
// ---------------------------------------------------------------------------
__global__ __launch_bounds__(256) void edge_kernel(
    const int* __restrict__ ei,
    const float* __restrict__ h,
    const float* __restrict__ alpha_s, const float* __restrict__ alpha_d,
    float* __restrict__ out)
{
    const unsigned total = (unsigned)N_EDGES * 32u;
    const unsigned stride = gridDim.x * blockDim.x;
    for (unsigned i = blockIdx.x * blockDim.x + threadIdx.x; i < total; i += stride) {
        const int e = (int)(i >> 5);
        const int c = (int)(i & 31);
        const int src = ei[e];
        const int dst = ei[N_EDGES + e];
        const int head = c >> 3;

        float att = alpha_s[src * 4 + head] + alpha_d[dst * 4 + head];
        att = att > 0.f ? att : NEG_SLOPE * att;

        const float4 hv = ((const float4*)h)[(size_t)src * 32 + c];
        float* po = out + (size_t)dst * 128 + c * 4;
        atomicAdd(po + 0, att * hv.x);
        atomicAdd(po + 1, att * hv.y);
        atomicAdd(po + 2, att * hv.z);
        atomicAdd(po + 3, att * hv.w);
    }
}

extern "C" void kernel_launch(void* const* d_in, const int* in_sizes, int n_in,
                              void* d_out, int out_size, void* d_ws, size_t ws_size,
                              hipStream_t stream) {
    const float* x  = (const float*)d_in[0];
    const int*   ei = (const int*)d_in[1];
    const float* W  = (const float*)d_in[2];
    const float* a  = (const float*)d_in[3];
    float* out = (float*)d_out;

    // Workspace layout (floats / ints):
    //   h        : N_NODES*128 f32              (25.6 MB)
    //   alpha_s  : N_NODES*4  f32               (0.8 MB)
    //   alpha_d  : N_NODES*4  f32               (0.8 MB)
    //   deg      : N_NODES    i32               (0.2 MB)
    //   cursor   : N_NODES    i32               (0.2 MB)
    //   srcs     : N_EDGES    i32               (6.4 MB)
    float* h  = (float*)d_ws;
    float* as = h + (size_t)N_NODES * 128;
    float* ad = as + (size_t)N_NODES * 4;
    int* deg    = (int*)(ad + (size_t)N_NODES * 4);
    int* cursor = deg + N_NODES;
    int* srcs   = cursor + N_NODES;
    const size_t needed = ((size_t)N_NODES * 136 + N_EDGES) * 4;

    gemm_alpha_kernel<<<N_NODES / 8, 256, 0, stream>>>(x, W, a, h, as, ad);

    if (ws_size >= needed) {
        hipMemsetAsync(deg, 0, N_NODES * sizeof(int), stream);
        hist_kernel<<<2048, 256, 0, stream>>>(ei, deg);
        scan_kernel<<<1, 1024, 0, stream>>>(deg, cursor);
        scatter_kernel<<<2048, 256, 0, stream>>>(ei, cursor, srcs);
        gather_kernel<<<(N_NODES * 64 + 255) / 256, 256, 0, stream>>>(
            srcs, cursor, deg, h, as, ad, out);
    } else {
        hipMemsetAsync(d_out, 0, (size_t)out_size * sizeof(float), stream);
        edge_kernel<<<4096, 256, 0, stream>>>(ei, h, as, ad, out);
    }
}

// Round 4
// 245.606 us; speedup vs baseline: 11.3361x; 1.9812x over previous
//
#include <hip/hip_runtime.h>

#define N_NODES 50000
#define N_EDGES 1600000
#define IN_F 128
#define OUT_F 128   // HEADS*HEAD_DIM
#define HEADS 4
#define HEAD_DIM 32
#define NEG_SLOPE 0.2f

#define NB 196        // coarse buckets: bucket = dst >> 8 (256 nodes each)
#define CAP 9216      // per-bucket capacity (mean 8192, +11 sigma)
#define P1_EPT 16     // phase-1 edges per thread
#define P1_EPB (P1_EPT * 256)

// ---------------------------------------------------------------------------
// Kernel A: h = x @ W^T  plus per-node attention scalars
//   alpha_s[n][head] = sum_d h[n,head,d] * a[head][d]
//   alpha_d[n][head] = sum_d h[n,head,d] * a[head][32+d]
// ---------------------------------------------------------------------------
__global__ __launch_bounds__(256) void gemm_alpha_kernel(
    const float* __restrict__ x, const float* __restrict__ W,
    const float* __restrict__ a,
    float* __restrict__ h, float* __restrict__ alpha_s, float* __restrict__ alpha_d)
{
    __shared__ float Wlds[128][129];
    __shared__ float xs[8][128];

    const int tid = threadIdx.x;
    const int node0 = blockIdx.x * 8;

    {
        const float4* W4 = (const float4*)W;
        #pragma unroll
        for (int it = 0; it < 16; ++it) {
            int i = tid + it * 256;
            int o = i >> 5, k4 = i & 31;
            float4 w = W4[i];
            Wlds[o][k4 * 4 + 0] = w.x;
            Wlds[o][k4 * 4 + 1] = w.y;
            Wlds[o][k4 * 4 + 2] = w.z;
            Wlds[o][k4 * 4 + 3] = w.w;
        }
    }
    {
        const float4* x4 = (const float4*)x;
        int n = tid >> 5, k4 = tid & 31;
        float4 v = x4[(size_t)(node0 + n) * 32 + k4];
        xs[n][k4 * 4 + 0] = v.x;
        xs[n][k4 * 4 + 1] = v.y;
        xs[n][k4 * 4 + 2] = v.z;
        xs[n][k4 * 4 + 3] = v.w;
    }
    __syncthreads();

    const int o = tid & 127;
    const int g = tid >> 7;
    const int nbase = g * 4;

    float acc0 = 0.f, acc1 = 0.f, acc2 = 0.f, acc3 = 0.f;
    #pragma unroll 8
    for (int kc = 0; kc < 32; ++kc) {
        float w0 = Wlds[o][kc * 4 + 0];
        float w1 = Wlds[o][kc * 4 + 1];
        float w2 = Wlds[o][kc * 4 + 2];
        float w3 = Wlds[o][kc * 4 + 3];
        float4 xv0 = *(const float4*)&xs[nbase + 0][kc * 4];
        float4 xv1 = *(const float4*)&xs[nbase + 1][kc * 4];
        float4 xv2 = *(const float4*)&xs[nbase + 2][kc * 4];
        float4 xv3 = *(const float4*)&xs[nbase + 3][kc * 4];
        acc0 = fmaf(w0, xv0.x, fmaf(w1, xv0.y, fmaf(w2, xv0.z, fmaf(w3, xv0.w, acc0))));
        acc1 = fmaf(w0, xv1.x, fmaf(w1, xv1.y, fmaf(w2, xv1.z, fmaf(w3, xv1.w, acc1))));
        acc2 = fmaf(w0, xv2.x, fmaf(w1, xv2.y, fmaf(w2, xv2.z, fmaf(w3, xv2.w, acc2))));
        acc3 = fmaf(w0, xv3.x, fmaf(w1, xv3.y, fmaf(w2, xv3.z, fmaf(w3, xv3.w, acc3))));
    }

    const int head = o >> 5;
    const int d = o & 31;
    const float a_s = a[head * 64 + d];
    const float a_d = a[head * 64 + 32 + d];

    float accs[4] = {acc0, acc1, acc2, acc3};
    #pragma unroll
    for (int n = 0; n < 4; ++n) {
        const int node = node0 + nbase + n;
        h[(size_t)node * 128 + o] = accs[n];
        float s = accs[n] * a_s;
        float t = accs[n] * a_d;
        #pragma unroll
        for (int off = 16; off >= 1; off >>= 1) {
            s += __shfl_xor(s, off);
            t += __shfl_xor(t, off);
        }
        if (d == 0) {
            alpha_s[node * 4 + head] = s;
            alpha_d[node * 4 + head] = t;
        }
    }
}

__global__ void init_cursor_kernel(int* __restrict__ gcursor) {
    int t = blockIdx.x * blockDim.x + threadIdx.x;
    if (t < NB) gcursor[t] = t * CAP;
}

// ---------------------------------------------------------------------------
// Phase 1: partition edges into NB coarse buckets (bucket = dst>>8).
// Block-local LDS histogram -> one global atomic per (block,bucket) -> packed
// entry (dst&255)<<16 | src written to part[]. Writes cluster into ~21-entry
// contiguous runs per (block,bucket) -> L2 write-coalesced.
// ---------------------------------------------------------------------------
__global__ __launch_bounds__(256) void part_kernel(
    const int* __restrict__ ei, int* __restrict__ gcursor,
    unsigned* __restrict__ part)
{
    __shared__ int cnt[NB];
    __shared__ int gbase[NB];
    const int tid = threadIdx.x;
    const int e0 = blockIdx.x * P1_EPB;

    for (int i = tid; i < NB; i += 256) cnt[i] = 0;
    __syncthreads();

    unsigned pk[P1_EPT];
    int bk[P1_EPT];
    int loc[P1_EPT];
    #pragma unroll
    for (int k = 0; k < P1_EPT; ++k) {
        int e = e0 + k * 256 + tid;
        bk[k] = -1;
        if (e < N_EDGES) {
            int src = ei[e];
            int dst = ei[N_EDGES + e];
            int b = dst >> 8;
            bk[k] = b;
            pk[k] = ((unsigned)(dst & 255) << 16) | (unsigned)src;
            loc[k] = atomicAdd(&cnt[b], 1);
        }
    }
    __syncthreads();
    for (int b = tid; b < NB; b += 256)
        gbase[b] = atomicAdd(&gcursor[b], cnt[b]);
    __syncthreads();
    #pragma unroll
    for (int k = 0; k < P1_EPT; ++k)
        if (bk[k] >= 0)
            part[gbase[bk[k]] + loc[k]] = pk[k];
}

// ---------------------------------------------------------------------------
// Phase 2: one block per bucket. Stage entries in LDS, 256-bin histogram +
// scan -> node_start/node_cnt, LDS scatter to dst-sorted ushort src list,
// coalesced writeout.
// ---------------------------------------------------------------------------
__global__ __launch_bounds__(256) void bucket_kernel(
    const int* __restrict__ gcursor, const unsigned* __restrict__ part,
    unsigned short* __restrict__ srcs16,
    int* __restrict__ node_start, int* __restrict__ node_cnt)
{
    __shared__ unsigned ent[CAP];
    __shared__ unsigned short srt[CAP];
    __shared__ int cnt[256];
    __shared__ int s[256];
    __shared__ int cur[256];

    const int b = blockIdx.x;
    const int tid = threadIdx.x;
    const int bstart = b * CAP;
    int n_b = gcursor[b] - bstart;
    if (n_b > CAP) n_b = CAP;   // safety clamp

    cnt[tid] = 0;
    __syncthreads();

    for (int i = tid; i < n_b; i += 256) {
        unsigned e = part[bstart + i];
        ent[i] = e;
        atomicAdd(&cnt[e >> 16], 1);
    }
    __syncthreads();

    // exclusive scan over 256 bins (Hillis-Steele)
    int c = cnt[tid];
    s[tid] = c;
    __syncthreads();
    #pragma unroll
    for (int off = 1; off < 256; off <<= 1) {
        int v = (tid >= off) ? s[tid - off] : 0;
        __syncthreads();
        s[tid] += v;
        __syncthreads();
    }
    const int ebase = s[tid] - c;
    cur[tid] = ebase;
    const int node = b * 256 + tid;
    if (node < N_NODES) {
        node_start[node] = bstart + ebase;
        node_cnt[node] = c;
    }
    __syncthreads();

    for (int i = tid; i < n_b; i += 256) {
        unsigned e = ent[i];
        int loc = atomicAdd(&cur[e >> 16], 1);
        srt[loc] = (unsigned short)(e & 0xFFFFu);
    }
    __syncthreads();

    // coalesced writeout (2 ushorts per u32)
    const unsigned* srt32 = (const unsigned*)srt;
    unsigned* dst32 = (unsigned*)(srcs16 + bstart);
    const int nw = (n_b + 1) >> 1;
    for (int i = tid; i < nw; i += 256) dst32[i] = srt32[i];
}

// ---------------------------------------------------------------------------
// Gather: one wave per dst node, lane owns float2 of the feature row.
// out row written exactly once -> no atomics, no output memset.
// ---------------------------------------------------------------------------
__global__ __launch_bounds__(256) void gather_kernel(
    const unsigned short* __restrict__ srcs,
    const int* __restrict__ node_start, const int* __restrict__ node_cnt,
    const float* __restrict__ h,
    const float* __restrict__ alpha_s, const float* __restrict__ alpha_d,
    float* __restrict__ out)
{
    const int wid = (blockIdx.x * 256 + threadIdx.x) >> 6;
    if (wid >= N_NODES) return;
    const int lane = threadIdx.x & 63;
    const int start = node_start[wid];
    const int end = start + node_cnt[wid];
    const int head = lane >> 4;

    const float adv = alpha_d[wid * 4 + head];
    const float2* __restrict__ h2 = (const float2*)h;

    float2 acc0 = {0.f, 0.f}, acc1 = {0.f, 0.f};
    int i = start;
    for (; i + 1 < end; i += 2) {
        int s0 = srcs[i];
        int s1 = srcs[i + 1];
        float att0 = alpha_s[s0 * 4 + head] + adv;
        float att1 = alpha_s[s1 * 4 + head] + adv;
        att0 = att0 > 0.f ? att0 : NEG_SLOPE * att0;
        att1 = att1 > 0.f ? att1 : NEG_SLOPE * att1;
        float2 hv0 = h2[(size_t)s0 * 64 + lane];
        float2 hv1 = h2[(size_t)s1 * 64 + lane];
        acc0.x = fmaf(att0, hv0.x, acc0.x);
        acc0.y = fmaf(att0, hv0.y, acc0.y);
        acc1.x = fmaf(att1, hv1.x, acc1.x);
        acc1.y = fmaf(att1, hv1.y, acc1.y);
    }
    if (i < end) {
        int s0 = srcs[i];
        float att0 = alpha_s[s0 * 4 + head] + adv;
        att0 = att0 > 0.f ? att0 : NEG_SLOPE * att0;
        float2 hv0 = h2[(size_t)s0 * 64 + lane];
        acc0.x = fmaf(att0, hv0.x, acc0.x);
        acc0.y = fmaf(att0, hv0.y, acc0.y);
    }
    float2 r = {acc0.x + acc1.x, acc0.y + acc1.y};
    ((float2*)out)[(size_t)wid * 64 + lane] = r;
}

// ---------------------------------------------------------------------------
// Fallback atomic edge kernel (only if ws_size too small for the sort path).
// ---------------------------------------------------------------------------
__global__ __launch_bounds__(256) void edge_kernel(
    const int* __restrict__ ei,
    const float* __restrict__ h,
    const float* __restrict__ alpha_s, const float* __restrict__ alpha_d,
    float* __restrict__ out)
{
    const unsigned total = (unsigned)N_EDGES * 32u;
    const unsigned stride = gridDim.x * blockDim.x;
    for (unsigned i = blockIdx.x * blockDim.x + threadIdx.x; i < total; i += stride) {
        const int e = (int)(i >> 5);
        const int c = (int)(i & 31);
        const int src = ei[e];
        const int dst = ei[N_EDGES + e];
        const int head = c >> 3;

        float att = alpha_s[src * 4 + head] + alpha_d[dst * 4 + head];
        att = att > 0.f ? att : NEG_SLOPE * att;

        const float4 hv = ((const float4*)h)[(size_t)src * 32 + c];
        float* po = out + (size_t)dst * 128 + c * 4;
        atomicAdd(po + 0, att * hv.x);
        atomicAdd(po + 1, att * hv.y);
        atomicAdd(po + 2, att * hv.z);
        atomicAdd(po + 3, att * hv.w);
    }
}

extern "C" void kernel_launch(void* const* d_in, const int* in_sizes, int n_in,
                              void* d_out, int out_size, void* d_ws, size_t ws_size,
                              hipStream_t stream) {
    const float* x  = (const float*)d_in[0];
    const int*   ei = (const int*)d_in[1];
    const float* W  = (const float*)d_in[2];
    const float* a  = (const float*)d_in[3];
    float* out = (float*)d_out;

    // Workspace layout:
    //   h          : N_NODES*128 f32   (25.6 MB)
    //   alpha_s    : N_NODES*4  f32    (0.8 MB)
    //   alpha_d    : N_NODES*4  f32    (0.8 MB)
    //   part       : NB*CAP u32        (7.2 MB)
    //   srcs16     : NB*CAP u16        (3.6 MB)
    //   gcursor    : NB i32
    //   node_start : 50176 i32         (0.2 MB)
    //   node_cnt   : 50176 i32         (0.2 MB)
    float* h  = (float*)d_ws;
    float* as = h + (size_t)N_NODES * 128;
    float* ad = as + (size_t)N_NODES * 4;
    unsigned* part = (unsigned*)(ad + (size_t)N_NODES * 4);
    unsigned short* srcs16 = (unsigned short*)(part + (size_t)NB * CAP);
    int* gcursor = (int*)(srcs16 + (size_t)NB * CAP);
    int* node_start = gcursor + 256;            // NB rounded up
    int* node_cnt   = node_start + 50176;
    const size_t needed = (size_t)((char*)(node_cnt + 50176) - (char*)d_ws);

    gemm_alpha_kernel<<<N_NODES / 8, 256, 0, stream>>>(x, W, a, h, as, ad);

    if (ws_size >= needed) {
        init_cursor_kernel<<<1, 256, 0, stream>>>(gcursor);
        part_kernel<<<(N_EDGES + P1_EPB - 1) / P1_EPB, 256, 0, stream>>>(ei, gcursor, part);
        bucket_kernel<<<NB, 256, 0, stream>>>(gcursor, part, srcs16, node_start, node_cnt);
        gather_kernel<<<(N_NODES * 64 + 255) / 256, 256, 0, stream>>>(
            srcs16, node_start, node_cnt, h, as, ad, out);
    } else {
        hipMemsetAsync(d_out, 0, (size_t)out_size * sizeof(float), stream);
        edge_kernel<<<4096, 256, 0, stream>>>(ei, h, as, ad, out);
    }
}

// Round 5
// 218.378 us; speedup vs baseline: 12.7496x; 1.1247x over previous
//
#include <hip/hip_runtime.h>

#define N_NODES 50000
#define N_EDGES 1600000
#define IN_F 128
#define OUT_F 128   // HEADS*HEAD_DIM
#define HEADS 4
#define HEAD_DIM 32
#define NEG_SLOPE 0.2f

#define NB 196        // coarse buckets: bucket = dst >> 8 (256 nodes each)
#define CAP 9216      // per-bucket capacity (mean 8192, +11 sigma)
#define P1_EPT 16     // phase-1 edges per thread
#define P1_EPB (P1_EPT * 256)

__device__ __forceinline__ unsigned short f2bf(float f) {
    unsigned u = __builtin_bit_cast(unsigned, f);
    u += 0x7FFFu + ((u >> 16) & 1u);   // round-to-nearest-even
    return (unsigned short)(u >> 16);
}
__device__ __forceinline__ float bf_lo(unsigned v) {   // low ushort -> float
    return __builtin_bit_cast(float, v << 16);
}
__device__ __forceinline__ float bf_hi(unsigned v) {   // high ushort -> float
    return __builtin_bit_cast(float, v & 0xFFFF0000u);
}

// ---------------------------------------------------------------------------
// Kernel A: h = x @ W^T  (bf16 storage) plus per-node attention scalars (fp32)
// ---------------------------------------------------------------------------
__global__ __launch_bounds__(256) void gemm_alpha_kernel(
    const float* __restrict__ x, const float* __restrict__ W,
    const float* __restrict__ a,
    unsigned short* __restrict__ hb,
    float* __restrict__ alpha_s, float* __restrict__ alpha_d)
{
    __shared__ float Wlds[128][129];
    __shared__ float xs[8][128];

    const int tid = threadIdx.x;
    const int node0 = blockIdx.x * 8;

    {
        const float4* W4 = (const float4*)W;
        #pragma unroll
        for (int it = 0; it < 16; ++it) {
            int i = tid + it * 256;
            int o = i >> 5, k4 = i & 31;
            float4 w = W4[i];
            Wlds[o][k4 * 4 + 0] = w.x;
            Wlds[o][k4 * 4 + 1] = w.y;
            Wlds[o][k4 * 4 + 2] = w.z;
            Wlds[o][k4 * 4 + 3] = w.w;
        }
    }
    {
        const float4* x4 = (const float4*)x;
        int n = tid >> 5, k4 = tid & 31;
        float4 v = x4[(size_t)(node0 + n) * 32 + k4];
        xs[n][k4 * 4 + 0] = v.x;
        xs[n][k4 * 4 + 1] = v.y;
        xs[n][k4 * 4 + 2] = v.z;
        xs[n][k4 * 4 + 3] = v.w;
    }
    __syncthreads();

    const int o = tid & 127;
    const int g = tid >> 7;
    const int nbase = g * 4;

    float acc0 = 0.f, acc1 = 0.f, acc2 = 0.f, acc3 = 0.f;
    #pragma unroll 8
    for (int kc = 0; kc < 32; ++kc) {
        float w0 = Wlds[o][kc * 4 + 0];
        float w1 = Wlds[o][kc * 4 + 1];
        float w2 = Wlds[o][kc * 4 + 2];
        float w3 = Wlds[o][kc * 4 + 3];
        float4 xv0 = *(const float4*)&xs[nbase + 0][kc * 4];
        float4 xv1 = *(const float4*)&xs[nbase + 1][kc * 4];
        float4 xv2 = *(const float4*)&xs[nbase + 2][kc * 4];
        float4 xv3 = *(const float4*)&xs[nbase + 3][kc * 4];
        acc0 = fmaf(w0, xv0.x, fmaf(w1, xv0.y, fmaf(w2, xv0.z, fmaf(w3, xv0.w, acc0))));
        acc1 = fmaf(w0, xv1.x, fmaf(w1, xv1.y, fmaf(w2, xv1.z, fmaf(w3, xv1.w, acc1))));
        acc2 = fmaf(w0, xv2.x, fmaf(w1, xv2.y, fmaf(w2, xv2.z, fmaf(w3, xv2.w, acc2))));
        acc3 = fmaf(w0, xv3.x, fmaf(w1, xv3.y, fmaf(w2, xv3.z, fmaf(w3, xv3.w, acc3))));
    }

    const int head = o >> 5;
    const int d = o & 31;
    const float a_s = a[head * 64 + d];
    const float a_d = a[head * 64 + 32 + d];

    float accs[4] = {acc0, acc1, acc2, acc3};
    #pragma unroll
    for (int n = 0; n < 4; ++n) {
        const int node = node0 + nbase + n;
        hb[(size_t)node * 128 + o] = f2bf(accs[n]);
        float s = accs[n] * a_s;
        float t = accs[n] * a_d;
        #pragma unroll
        for (int off = 16; off >= 1; off >>= 1) {
            s += __shfl_xor(s, off);
            t += __shfl_xor(t, off);
        }
        if (d == 0) {
            alpha_s[node * 4 + head] = s;
            alpha_d[node * 4 + head] = t;
        }
    }
}

__global__ void init_cursor_kernel(int* __restrict__ gcursor) {
    int t = blockIdx.x * blockDim.x + threadIdx.x;
    if (t < NB) gcursor[t] = t * CAP;
}

// ---------------------------------------------------------------------------
// Phase 1: partition edges into NB coarse buckets (bucket = dst>>8).
// ---------------------------------------------------------------------------
__global__ __launch_bounds__(256) void part_kernel(
    const int* __restrict__ ei, int* __restrict__ gcursor,
    unsigned* __restrict__ part)
{
    __shared__ int cnt[NB];
    __shared__ int gbase[NB];
    const int tid = threadIdx.x;
    const int e0 = blockIdx.x * P1_EPB;

    for (int i = tid; i < NB; i += 256) cnt[i] = 0;
    __syncthreads();

    unsigned pk[P1_EPT];
    int bk[P1_EPT];
    int loc[P1_EPT];
    #pragma unroll
    for (int k = 0; k < P1_EPT; ++k) {
        int e = e0 + k * 256 + tid;
        bk[k] = -1;
        if (e < N_EDGES) {
            int src = ei[e];
            int dst = ei[N_EDGES + e];
            int b = dst >> 8;
            bk[k] = b;
            pk[k] = ((unsigned)(dst & 255) << 16) | (unsigned)src;
            loc[k] = atomicAdd(&cnt[b], 1);
        }
    }
    __syncthreads();
    for (int b = tid; b < NB; b += 256)
        gbase[b] = atomicAdd(&gcursor[b], cnt[b]);
    __syncthreads();
    #pragma unroll
    for (int k = 0; k < P1_EPT; ++k)
        if (bk[k] >= 0)
            part[gbase[bk[k]] + loc[k]] = pk[k];
}

// ---------------------------------------------------------------------------
// Phase 2: one block per bucket -> dst-sorted ushort src list + node offsets.
// ---------------------------------------------------------------------------
__global__ __launch_bounds__(256) void bucket_kernel(
    const int* __restrict__ gcursor, const unsigned* __restrict__ part,
    unsigned short* __restrict__ srcs16,
    int* __restrict__ node_start, int* __restrict__ node_cnt)
{
    __shared__ unsigned ent[CAP];
    __shared__ unsigned short srt[CAP];
    __shared__ int cnt[256];
    __shared__ int s[256];
    __shared__ int cur[256];

    const int b = blockIdx.x;
    const int tid = threadIdx.x;
    const int bstart = b * CAP;
    int n_b = gcursor[b] - bstart;
    if (n_b > CAP) n_b = CAP;

    cnt[tid] = 0;
    __syncthreads();

    for (int i = tid; i < n_b; i += 256) {
        unsigned e = part[bstart + i];
        ent[i] = e;
        atomicAdd(&cnt[e >> 16], 1);
    }
    __syncthreads();

    int c = cnt[tid];
    s[tid] = c;
    __syncthreads();
    #pragma unroll
    for (int off = 1; off < 256; off <<= 1) {
        int v = (tid >= off) ? s[tid - off] : 0;
        __syncthreads();
        s[tid] += v;
        __syncthreads();
    }
    const int ebase = s[tid] - c;
    cur[tid] = ebase;
    const int node = b * 256 + tid;
    if (node < N_NODES) {
        node_start[node] = bstart + ebase;
        node_cnt[node] = c;
    }
    __syncthreads();

    for (int i = tid; i < n_b; i += 256) {
        unsigned e = ent[i];
        int loc = atomicAdd(&cur[e >> 16], 1);
        srt[loc] = (unsigned short)(e & 0xFFFFu);
    }
    __syncthreads();

    const unsigned* srt32 = (const unsigned*)srt;
    unsigned* dst32 = (unsigned*)(srcs16 + bstart);
    const int nw = (n_b + 1) >> 1;
    for (int i = tid; i < nw; i += 256) dst32[i] = srt32[i];
}

// ---------------------------------------------------------------------------
// Gather: one wave per dst node. Lane owns features (2*lane, 2*lane+1) of the
// bf16 h row (one dword load per edge per lane). fp32 accumulate, write once.
// ---------------------------------------------------------------------------
__global__ __launch_bounds__(256) void gather_kernel(
    const unsigned short* __restrict__ srcs,
    const int* __restrict__ node_start, const int* __restrict__ node_cnt,
    const unsigned* __restrict__ h32,       // bf16 h, viewed as dwords
    const float* __restrict__ alpha_s, const float* __restrict__ alpha_d,
    float* __restrict__ out)
{
    const int wid = (blockIdx.x * 256 + threadIdx.x) >> 6;
    if (wid >= N_NODES) return;
    const int lane = threadIdx.x & 63;
    const int start = node_start[wid];
    const int end = start + node_cnt[wid];
    const int head = lane >> 4;

    const float adv = alpha_d[wid * 4 + head];

    float ax = 0.f, ay = 0.f, bx = 0.f, by = 0.f;
    int i = start;
    for (; i + 1 < end; i += 2) {
        int s0 = srcs[i];
        int s1 = srcs[i + 1];
        float att0 = alpha_s[s0 * 4 + head] + adv;
        float att1 = alpha_s[s1 * 4 + head] + adv;
        att0 = att0 > 0.f ? att0 : NEG_SLOPE * att0;
        att1 = att1 > 0.f ? att1 : NEG_SLOPE * att1;
        unsigned v0 = h32[(size_t)s0 * 64 + lane];
        unsigned v1 = h32[(size_t)s1 * 64 + lane];
        ax = fmaf(att0, bf_lo(v0), ax);
        ay = fmaf(att0, bf_hi(v0), ay);
        bx = fmaf(att1, bf_lo(v1), bx);
        by = fmaf(att1, bf_hi(v1), by);
    }
    if (i < end) {
        int s0 = srcs[i];
        float att0 = alpha_s[s0 * 4 + head] + adv;
        att0 = att0 > 0.f ? att0 : NEG_SLOPE * att0;
        unsigned v0 = h32[(size_t)s0 * 64 + lane];
        ax = fmaf(att0, bf_lo(v0), ax);
        ay = fmaf(att0, bf_hi(v0), ay);
    }
    float2 r = {ax + bx, ay + by};
    ((float2*)out)[(size_t)wid * 64 + lane] = r;
}

// ---------------------------------------------------------------------------
// Fallback atomic edge kernel (only if ws_size too small for the sort path).
// ---------------------------------------------------------------------------
__global__ __launch_bounds__(256) void edge_kernel(
    const int* __restrict__ ei,
    const unsigned* __restrict__ h32,
    const float* __restrict__ alpha_s, const float* __restrict__ alpha_d,
    float* __restrict__ out)
{
    const unsigned total = (unsigned)N_EDGES * 32u;
    const unsigned stride = gridDim.x * blockDim.x;
    for (unsigned i = blockIdx.x * blockDim.x + threadIdx.x; i < total; i += stride) {
        const int e = (int)(i >> 5);
        const int c = (int)(i & 31);
        const int src = ei[e];
        const int dst = ei[N_EDGES + e];
        const int head = c >> 3;

        float att = alpha_s[src * 4 + head] + alpha_d[dst * 4 + head];
        att = att > 0.f ? att : NEG_SLOPE * att;

        unsigned v0 = h32[(size_t)src * 64 + c * 2];
        unsigned v1 = h32[(size_t)src * 64 + c * 2 + 1];
        float* po = out + (size_t)dst * 128 + c * 4;
        atomicAdd(po + 0, att * bf_lo(v0));
        atomicAdd(po + 1, att * bf_hi(v0));
        atomicAdd(po + 2, att * bf_lo(v1));
        atomicAdd(po + 3, att * bf_hi(v1));
    }
}

extern "C" void kernel_launch(void* const* d_in, const int* in_sizes, int n_in,
                              void* d_out, int out_size, void* d_ws, size_t ws_size,
                              hipStream_t stream) {
    const float* x  = (const float*)d_in[0];
    const int*   ei = (const int*)d_in[1];
    const float* W  = (const float*)d_in[2];
    const float* a  = (const float*)d_in[3];
    float* out = (float*)d_out;

    // Workspace layout:
    //   hb         : N_NODES*128 bf16  (12.8 MB)
    //   alpha_s    : N_NODES*4  f32    (0.8 MB)
    //   alpha_d    : N_NODES*4  f32    (0.8 MB)
    //   part       : NB*CAP u32        (7.2 MB)
    //   srcs16     : NB*CAP u16        (3.6 MB)
    //   gcursor    : 256 i32
    //   node_start : 50176 i32
    //   node_cnt   : 50176 i32
    unsigned short* hb = (unsigned short*)d_ws;
    float* as = (float*)(hb + (size_t)N_NODES * 128);
    float* ad = as + (size_t)N_NODES * 4;
    unsigned* part = (unsigned*)(ad + (size_t)N_NODES * 4);
    unsigned short* srcs16 = (unsigned short*)(part + (size_t)NB * CAP);
    int* gcursor = (int*)(srcs16 + (size_t)NB * CAP);
    int* node_start = gcursor + 256;
    int* node_cnt   = node_start + 50176;
    const size_t needed = (size_t)((char*)(node_cnt + 50176) - (char*)d_ws);

    gemm_alpha_kernel<<<N_NODES / 8, 256, 0, stream>>>(x, W, a, hb, as, ad);

    if (ws_size >= needed) {
        init_cursor_kernel<<<1, 256, 0, stream>>>(gcursor);
        part_kernel<<<(N_EDGES + P1_EPB - 1) / P1_EPB, 256, 0, stream>>>(ei, gcursor, part);
        bucket_kernel<<<NB, 256, 0, stream>>>(gcursor, part, srcs16, node_start, node_cnt);
        gather_kernel<<<(N_NODES * 64 + 255) / 256, 256, 0, stream>>>(
            srcs16, node_start, node_cnt, (const unsigned*)hb, as, ad, out);
    } else {
        hipMemsetAsync(d_out, 0, (size_t)out_size * sizeof(float), stream);
        edge_kernel<<<4096, 256, 0, stream>>>(ei, (const unsigned*)hb, as, ad, out);
    }
}

// Round 6
// 137.904 us; speedup vs baseline: 20.1895x; 1.5835x over previous
//
#include <hip/hip_runtime.h>

#define N_NODES 50000
#define N_EDGES 1600000
#define IN_F 128
#define OUT_F 128   // HEADS*HEAD_DIM
#define HEADS 4
#define HEAD_DIM 32
#define NEG_SLOPE 0.2f

#define NB 196        // coarse buckets: bucket = dst >> 8 (256 nodes each)
#define CAP 9216      // per-bucket capacity (mean 8192, +11 sigma)
#define P1_EPT 16     // phase-1 edges per thread
#define P1_EPB (P1_EPT * 256)

typedef __attribute__((ext_vector_type(8))) short short8v;
typedef __attribute__((ext_vector_type(4))) float f32x4;

__device__ __forceinline__ unsigned short f2bf(float f) {
    unsigned u = __builtin_bit_cast(unsigned, f);
    u += 0x7FFFu + ((u >> 16) & 1u);   // round-to-nearest-even
    return (unsigned short)(u >> 16);
}
__device__ __forceinline__ float bf_lo(unsigned v) {
    return __builtin_bit_cast(float, v << 16);
}
__device__ __forceinline__ float bf_hi(unsigned v) {
    return __builtin_bit_cast(float, v & 0xFFFF0000u);
}

// ---------------------------------------------------------------------------
// Prep: W fp32 -> bf16 (16384 elems) + init bucket cursors. 64 blocks.
// ---------------------------------------------------------------------------
__global__ __launch_bounds__(256) void prep_kernel(
    const float* __restrict__ W, unsigned short* __restrict__ wbf,
    int* __restrict__ gcursor)
{
    int t = blockIdx.x * 256 + threadIdx.x;
    if (t < 16384) wbf[t] = f2bf(W[t]);
    if (t < NB) gcursor[t] = t * CAP;
}

// ---------------------------------------------------------------------------
// GEMM via MFMA: h = x @ W^T, bf16 inputs, fp32 accum, bf16 h out.
// Block = 4 waves; wave w covers nodes [blk*64 + w*16, +16), all 128 outs.
// A-frag: lane l holds x[node0 + (l&15)][ks*32 + (l>>4)*8 + j] (same k-layout
// for B -> k-permutation cancels). C/D: col=lane&15, row=(lane>>4)*4+reg.
// W read from global bf16 (32KB, L1-resident). No LDS.
// ---------------------------------------------------------------------------
__global__ __launch_bounds__(256) void gemm_mfma_kernel(
    const float* __restrict__ x, const unsigned short* __restrict__ wbf,
    unsigned short* __restrict__ hb)
{
    const int tid = threadIdx.x;
    const int wave = tid >> 6;
    const int lane = tid & 63;
    const int lr = lane & 15;
    const int lg = lane >> 4;
    const int nodeA = blockIdx.x * 64 + wave * 16 + lr;
    const int nrow = nodeA < N_NODES ? nodeA : 0;

    f32x4 acc[8];
    #pragma unroll
    for (int i = 0; i < 8; ++i) acc[i] = (f32x4){0.f, 0.f, 0.f, 0.f};

    #pragma unroll
    for (int ks = 0; ks < 4; ++ks) {
        const float* xp = x + (size_t)nrow * 128 + ks * 32 + lg * 8;
        float4 xa = *(const float4*)xp;
        float4 xc = *(const float4*)(xp + 4);
        short8v afrag;
        afrag[0] = (short)f2bf(xa.x); afrag[1] = (short)f2bf(xa.y);
        afrag[2] = (short)f2bf(xa.z); afrag[3] = (short)f2bf(xa.w);
        afrag[4] = (short)f2bf(xc.x); afrag[5] = (short)f2bf(xc.y);
        afrag[6] = (short)f2bf(xc.z); afrag[7] = (short)f2bf(xc.w);
        #pragma unroll
        for (int nf = 0; nf < 8; ++nf) {
            const short8v bfrag = *(const short8v*)(wbf + (size_t)(nf * 16 + lr) * 128 + ks * 32 + lg * 8);
            acc[nf] = __builtin_amdgcn_mfma_f32_16x16x32_bf16(afrag, bfrag, acc[nf], 0, 0, 0);
        }
    }

    const int nbase = blockIdx.x * 64 + wave * 16 + lg * 4;
    #pragma unroll
    for (int reg = 0; reg < 4; ++reg) {
        const int n2 = nbase + reg;
        if (n2 < N_NODES) {
            unsigned short* hp = hb + (size_t)n2 * 128 + lr;
            #pragma unroll
            for (int nf = 0; nf < 8; ++nf)
                hp[nf * 16] = f2bf(acc[nf][reg]);
        }
    }
}

// ---------------------------------------------------------------------------
// Alpha: per-node attention scalars from bf16 h. Wave per node.
// lane owns features (2*lane, 2*lane+1); head = lane>>4.
// ---------------------------------------------------------------------------
__global__ __launch_bounds__(256) void alpha_kernel(
    const unsigned* __restrict__ h32, const float* __restrict__ a,
    float* __restrict__ alpha_s, float* __restrict__ alpha_d)
{
    const int wid = (blockIdx.x * 256 + threadIdx.x) >> 6;
    if (wid >= N_NODES) return;
    const int lane = threadIdx.x & 63;
    const int head = lane >> 4;
    const int d0 = (lane & 15) * 2;

    unsigned v = h32[(size_t)wid * 64 + lane];
    float h0 = bf_lo(v), h1 = bf_hi(v);
    float s = h0 * a[head * 64 + d0] + h1 * a[head * 64 + d0 + 1];
    float t = h0 * a[head * 64 + 32 + d0] + h1 * a[head * 64 + 32 + d0 + 1];
    #pragma unroll
    for (int off = 8; off >= 1; off >>= 1) {
        s += __shfl_xor(s, off);
        t += __shfl_xor(t, off);
    }
    if ((lane & 15) == 0) {
        alpha_s[wid * 4 + head] = s;
        alpha_d[wid * 4 + head] = t;
    }
}

// ---------------------------------------------------------------------------
// Phase 1: partition edges into NB coarse buckets (bucket = dst>>8).
// ---------------------------------------------------------------------------
__global__ __launch_bounds__(256) void part_kernel(
    const int* __restrict__ ei, int* __restrict__ gcursor,
    unsigned* __restrict__ part)
{
    __shared__ int cnt[NB];
    __shared__ int gbase[NB];
    const int tid = threadIdx.x;
    const int e0 = blockIdx.x * P1_EPB;

    for (int i = tid; i < NB; i += 256) cnt[i] = 0;
    __syncthreads();

    unsigned pk[P1_EPT];
    int bk[P1_EPT];
    int loc[P1_EPT];
    #pragma unroll
    for (int k = 0; k < P1_EPT; ++k) {
        int e = e0 + k * 256 + tid;
        bk[k] = -1;
        if (e < N_EDGES) {
            int src = ei[e];
            int dst = ei[N_EDGES + e];
            int b = dst >> 8;
            bk[k] = b;
            pk[k] = ((unsigned)(dst & 255) << 16) | (unsigned)src;
            loc[k] = atomicAdd(&cnt[b], 1);
        }
    }
    __syncthreads();
    for (int b = tid; b < NB; b += 256)
        gbase[b] = atomicAdd(&gcursor[b], cnt[b]);
    __syncthreads();
    #pragma unroll
    for (int k = 0; k < P1_EPT; ++k)
        if (bk[k] >= 0)
            part[gbase[bk[k]] + loc[k]] = pk[k];
}

// ---------------------------------------------------------------------------
// Phase 2: one block per bucket -> dst-sorted ushort src list + node offsets.
// ---------------------------------------------------------------------------
__global__ __launch_bounds__(256) void bucket_kernel(
    const int* __restrict__ gcursor, const unsigned* __restrict__ part,
    unsigned short* __restrict__ srcs16,
    int* __restrict__ node_start, int* __restrict__ node_cnt)
{
    __shared__ unsigned ent[CAP];
    __shared__ unsigned short srt[CAP];
    __shared__ int cnt[256];
    __shared__ int s[256];
    __shared__ int cur[256];

    const int b = blockIdx.x;
    const int tid = threadIdx.x;
    const int bstart = b * CAP;
    int n_b = gcursor[b] - bstart;
    if (n_b > CAP) n_b = CAP;

    cnt[tid] = 0;
    __syncthreads();

    for (int i = tid; i < n_b; i += 256) {
        unsigned e = part[bstart + i];
        ent[i] = e;
        atomicAdd(&cnt[e >> 16], 1);
    }
    __syncthreads();

    int c = cnt[tid];
    s[tid] = c;
    __syncthreads();
    #pragma unroll
    for (int off = 1; off < 256; off <<= 1) {
        int v = (tid >= off) ? s[tid - off] : 0;
        __syncthreads();
        s[tid] += v;
        __syncthreads();
    }
    const int ebase = s[tid] - c;
    cur[tid] = ebase;
    const int node = b * 256 + tid;
    if (node < N_NODES) {
        node_start[node] = bstart + ebase;
        node_cnt[node] = c;
    }
    __syncthreads();

    for (int i = tid; i < n_b; i += 256) {
        unsigned e = ent[i];
        int loc = atomicAdd(&cur[e >> 16], 1);
        srt[loc] = (unsigned short)(e & 0xFFFFu);
    }
    __syncthreads();

    const unsigned* srt32 = (const unsigned*)srt;
    unsigned* dst32 = (unsigned*)(srcs16 + bstart);
    const int nw = (n_b + 1) >> 1;
    for (int i = tid; i < nw; i += 256) dst32[i] = srt32[i];
}

// ---------------------------------------------------------------------------
// Gather: one wave per dst node, lane owns features (2*lane, 2*lane+1).
// 4-edge unroll -> 4 independent gather chains for latency hiding.
// ---------------------------------------------------------------------------
__global__ __launch_bounds__(256) void gather_kernel(
    const unsigned short* __restrict__ srcs,
    const int* __restrict__ node_start, const int* __restrict__ node_cnt,
    const unsigned* __restrict__ h32,
    const float* __restrict__ alpha_s, const float* __restrict__ alpha_d,
    float* __restrict__ out)
{
    const int wid = (blockIdx.x * 256 + threadIdx.x) >> 6;
    if (wid >= N_NODES) return;
    const int lane = threadIdx.x & 63;
    const int start = node_start[wid];
    const int end = start + node_cnt[wid];
    const int head = lane >> 4;

    const float adv = alpha_d[wid * 4 + head];

    float a0x = 0.f, a0y = 0.f, a1x = 0.f, a1y = 0.f;
    float a2x = 0.f, a2y = 0.f, a3x = 0.f, a3y = 0.f;
    int i = start;
    for (; i + 3 < end; i += 4) {
        int s0 = srcs[i], s1 = srcs[i + 1], s2 = srcs[i + 2], s3 = srcs[i + 3];
        float t0 = alpha_s[s0 * 4 + head] + adv;
        float t1 = alpha_s[s1 * 4 + head] + adv;
        float t2 = alpha_s[s2 * 4 + head] + adv;
        float t3 = alpha_s[s3 * 4 + head] + adv;
        t0 = t0 > 0.f ? t0 : NEG_SLOPE * t0;
        t1 = t1 > 0.f ? t1 : NEG_SLOPE * t1;
        t2 = t2 > 0.f ? t2 : NEG_SLOPE * t2;
        t3 = t3 > 0.f ? t3 : NEG_SLOPE * t3;
        unsigned v0 = h32[(size_t)s0 * 64 + lane];
        unsigned v1 = h32[(size_t)s1 * 64 + lane];
        unsigned v2 = h32[(size_t)s2 * 64 + lane];
        unsigned v3 = h32[(size_t)s3 * 64 + lane];
        a0x = fmaf(t0, bf_lo(v0), a0x); a0y = fmaf(t0, bf_hi(v0), a0y);
        a1x = fmaf(t1, bf_lo(v1), a1x); a1y = fmaf(t1, bf_hi(v1), a1y);
        a2x = fmaf(t2, bf_lo(v2), a2x); a2y = fmaf(t2, bf_hi(v2), a2y);
        a3x = fmaf(t3, bf_lo(v3), a3x); a3y = fmaf(t3, bf_hi(v3), a3y);
    }
    for (; i < end; ++i) {
        int s0 = srcs[i];
        float t0 = alpha_s[s0 * 4 + head] + adv;
        t0 = t0 > 0.f ? t0 : NEG_SLOPE * t0;
        unsigned v0 = h32[(size_t)s0 * 64 + lane];
        a0x = fmaf(t0, bf_lo(v0), a0x); a0y = fmaf(t0, bf_hi(v0), a0y);
    }
    float2 r = {(a0x + a1x) + (a2x + a3x), (a0y + a1y) + (a2y + a3y)};
    ((float2*)out)[(size_t)wid * 64 + lane] = r;
}

// ---------------------------------------------------------------------------
// Fallback atomic edge kernel (only if ws_size too small for the sort path).
// ---------------------------------------------------------------------------
__global__ __launch_bounds__(256) void edge_kernel(
    const int* __restrict__ ei,
    const unsigned* __restrict__ h32,
    const float* __restrict__ alpha_s, const float* __restrict__ alpha_d,
    float* __restrict__ out)
{
    const unsigned total = (unsigned)N_EDGES * 32u;
    const unsigned stride = gridDim.x * blockDim.x;
    for (unsigned i = blockIdx.x * blockDim.x + threadIdx.x; i < total; i += stride) {
        const int e = (int)(i >> 5);
        const int c = (int)(i & 31);
        const int src = ei[e];
        const int dst = ei[N_EDGES + e];
        const int head = c >> 3;

        float att = alpha_s[src * 4 + head] + alpha_d[dst * 4 + head];
        att = att > 0.f ? att : NEG_SLOPE * att;

        unsigned v0 = h32[(size_t)src * 64 + c * 2];
        unsigned v1 = h32[(size_t)src * 64 + c * 2 + 1];
        float* po = out + (size_t)dst * 128 + c * 4;
        atomicAdd(po + 0, att * bf_lo(v0));
        atomicAdd(po + 1, att * bf_hi(v0));
        atomicAdd(po + 2, att * bf_lo(v1));
        atomicAdd(po + 3, att * bf_hi(v1));
    }
}

extern "C" void kernel_launch(void* const* d_in, const int* in_sizes, int n_in,
                              void* d_out, int out_size, void* d_ws, size_t ws_size,
                              hipStream_t stream) {
    const float* x  = (const float*)d_in[0];
    const int*   ei = (const int*)d_in[1];
    const float* W  = (const float*)d_in[2];
    const float* a  = (const float*)d_in[3];
    float* out = (float*)d_out;

    // Workspace layout:
    //   hb         : N_NODES*128 bf16  (12.8 MB)
    //   alpha_s    : N_NODES*4  f32
    //   alpha_d    : N_NODES*4  f32
    //   part       : NB*CAP u32        (7.2 MB)
    //   srcs16     : NB*CAP u16        (3.6 MB)
    //   gcursor    : 256 i32
    //   node_start : 50176 i32
    //   node_cnt   : 50176 i32
    //   wbf        : 16384 bf16        (32 KB)
    unsigned short* hb = (unsigned short*)d_ws;
    float* as = (float*)(hb + (size_t)N_NODES * 128);
    float* ad = as + (size_t)N_NODES * 4;
    unsigned* part = (unsigned*)(ad + (size_t)N_NODES * 4);
    unsigned short* srcs16 = (unsigned short*)(part + (size_t)NB * CAP);
    int* gcursor = (int*)(srcs16 + (size_t)NB * CAP);
    int* node_start = gcursor + 256;
    int* node_cnt   = node_start + 50176;
    unsigned short* wbf = (unsigned short*)(node_cnt + 50176);
    const size_t needed = (size_t)((char*)(wbf + 16384) - (char*)d_ws);

    prep_kernel<<<64, 256, 0, stream>>>(W, wbf, gcursor);
    gemm_mfma_kernel<<<(N_NODES + 63) / 64, 256, 0, stream>>>(x, wbf, hb);
    alpha_kernel<<<(N_NODES * 64 + 255) / 256, 256, 0, stream>>>(
        (const unsigned*)hb, a, as, ad);

    if (ws_size >= needed) {
        part_kernel<<<(N_EDGES + P1_EPB - 1) / P1_EPB, 256, 0, stream>>>(ei, gcursor, part);
        bucket_kernel<<<NB, 256, 0, stream>>>(gcursor, part, srcs16, node_start, node_cnt);
        gather_kernel<<<(N_NODES * 64 + 255) / 256, 256, 0, stream>>>(
            srcs16, node_start, node_cnt, (const unsigned*)hb, as, ad, out);
    } else {
        hipMemsetAsync(d_out, 0, (size_t)out_size * sizeof(float), stream);
        edge_kernel<<<4096, 256, 0, stream>>>(ei, (const unsigned*)hb, as, ad, out);
    }
}